// Round 2
// baseline (564.028 us; speedup 1.0000x reference)
//
#include <hip/hip_runtime.h>

// Otsu-split loss, single streaming pass.
// f(i) = T2 - S(i)^2/i - (T-S(i))^2/(k-i)  -- s2 prefix cancels; only per-bin
// (count,sum) needed. LINEAR bins over [-16,16), width 1/256 (8192 bins):
// spreads N(0,1) data so LDS atomics don't collide (round-1 exp-binning
// concentrated ~200 hot bins -> 1.46M bank-conflict cycles, 350us).
// (count,sum) packed in ONE u64 LDS atomic: count<<42 | fixed20(v+16).
// Per-block bounds: count<=2^16 (22-bit field), sum<=2^16*2^25=2^41 (<2^42). Safe.

#define NBINS 8192
#define HIST_BLOCKS 512
#define HIST_THREADS 1024   // 64KB LDS/block -> 2 blocks/CU
#define FIN_THREADS 256
#define BPT (NBINS / FIN_THREADS)  // 32 bins per finalize thread

struct Scalars {
  unsigned long long kcount;
  double T;
  double T2;
};

__global__ __launch_bounds__(HIST_THREADS)
void k_hist(const float4* __restrict__ x4, const int4* __restrict__ m4, long n4,
            const float* __restrict__ x, const int* __restrict__ m, long n,
            Scalars* __restrict__ sc, unsigned* __restrict__ gcount,
            unsigned long long* __restrict__ gsum) {
  __shared__ unsigned long long hist[NBINS];   // exactly 64 KiB
  for (int b = threadIdx.x; b < NBINS; b += HIST_THREADS) hist[b] = 0ull;
  __syncthreads();

  long tid = (long)blockIdx.x * HIST_THREADS + threadIdx.x;
  long stride = (long)gridDim.x * HIST_THREADS;
  unsigned long long cnt = 0;
  double s = 0.0, s2 = 0.0;

#define PROC(vx, mv)                                                   \
  if (mv) {                                                            \
    float v = (vx);                                                    \
    int b = (int)fmaf(v, 256.0f, 4096.0f);                             \
    b = min(max(b, 0), NBINS - 1);                                     \
    long long q = llrintf(fmaf(v, 1048576.0f, 16777216.0f));           \
    q = q < 0 ? 0 : (q > (1ll << 25) ? (1ll << 25) : q);               \
    atomicAdd(&hist[b], (1ull << 42) + (unsigned long long)q);         \
    cnt++; s += (double)v; s2 += (double)v * (double)v;                \
  }

  for (long i = tid; i < n4; i += stride) {
    float4 xv = x4[i];
    int4 mv = m4[i];
    PROC(xv.x, mv.x)
    PROC(xv.y, mv.y)
    PROC(xv.z, mv.z)
    PROC(xv.w, mv.w)
  }
  if (tid == 0) {  // tail (n not multiple of 4)
    for (long i = n4 * 4; i < n; i++) { PROC(x[i], m[i]) }
  }
#undef PROC

  // wave-level reduce of scalar totals, one atomic trio per wave
  for (int off = 32; off > 0; off >>= 1) {
    cnt += __shfl_down(cnt, off);
    s   += __shfl_down(s, off);
    s2  += __shfl_down(s2, off);
  }
  if ((threadIdx.x & 63) == 0) {
    atomicAdd(&sc->kcount, cnt);
    atomicAdd(&sc->T, s);
    atomicAdd(&sc->T2, s2);
  }

  // flush nonzero bins, unpacked (global fields would be too tight packed)
  __syncthreads();
  for (int b = threadIdx.x; b < NBINS; b += HIST_THREADS) {
    unsigned long long h = hist[b];
    if (h) {
      atomicAdd(&gcount[b], (unsigned)(h >> 42));
      atomicAdd(&gsum[b], h & ((1ull << 42) - 1ull));
    }
  }
}

__global__ __launch_bounds__(FIN_THREADS)
void k_final(const Scalars* __restrict__ sc, const unsigned* __restrict__ gcount,
             const unsigned long long* __restrict__ gsum, float* __restrict__ out) {
  __shared__ unsigned long long scanC[FIN_THREADS];
  __shared__ unsigned long long scanS[FIN_THREADS];
  __shared__ double             rf[FIN_THREADS];
  __shared__ double             rS[FIN_THREADS];
  __shared__ unsigned long long rI[FIN_THREADS];
  int t = threadIdx.x;

  unsigned long long K = sc->kcount;
  double kd = (double)K;
  double T = sc->T, T2 = sc->T2;

  // per-thread chunk of BPT consecutive bins -> registers
  unsigned myC[BPT];
  unsigned long long myS[BPT];
  unsigned long long c = 0, s = 0;
  for (int j = 0; j < BPT; j++) {
    int b = t * BPT + j;
    myC[j] = gcount[b]; myS[j] = gsum[b];
    c += myC[j]; s += myS[j];
  }
  scanC[t] = c; scanS[t] = s;
  __syncthreads();
  // Hillis-Steele inclusive scan over thread-chunk totals
  for (int off = 1; off < FIN_THREADS; off <<= 1) {
    unsigned long long ac = (t >= off) ? scanC[t - off] : 0ull;
    unsigned long long as = (t >= off) ? scanS[t - off] : 0ull;
    __syncthreads();
    scanC[t] += ac; scanS[t] += as;
    __syncthreads();
  }
  unsigned long long Ci = scanC[t] - c;  // exclusive prefix
  unsigned long long Sq = scanS[t] - s;

  // evaluate f at every bin boundary, track argmin
  double bestf = 1.0e300, bestS = 0.0;
  unsigned long long bestI = 0;
  for (int j = 0; j < BPT; j++) {
    Ci += myC[j]; Sq += myS[j];
    if (Ci >= 1ull && Ci < K) {
      double di = (double)Ci;
      double S = (double)Sq * 9.5367431640625e-07 - 16.0 * di;  // *2^-20, un-bias
      double d2 = T - S;
      double f = T2 - S * S / di - d2 * d2 / (kd - di);
      if (f < bestf) { bestf = f; bestS = S; bestI = Ci; }
    }
  }
  rf[t] = bestf; rS[t] = bestS; rI[t] = bestI;
  __syncthreads();
  for (int off = FIN_THREADS / 2; off > 0; off >>= 1) {
    if (t < off && rf[t + off] < rf[t]) {
      rf[t] = rf[t + off]; rS[t] = rS[t + off]; rI[t] = rI[t + off];
    }
    __syncthreads();
  }
  if (t == 0) {
    double result = 0.0;
    if (K >= 2ull && rI[0] >= 1ull) {
      double var_tot = (T2 - T * T / kd) / kd;
      double reg = rf[0] / var_tot / kd;
      double pos_mean = rS[0] / (double)rI[0];
      result = pos_mean + 0.5 * reg;
    }
    out[0] = (float)result;
  }
}

extern "C" void kernel_launch(void* const* d_in, const int* in_sizes, int n_in,
                              void* d_out, int out_size, void* d_ws, size_t ws_size,
                              hipStream_t stream) {
  const float* x = (const float*)d_in[0];
  const int* m = (const int*)d_in[1];
  long n = (long)in_sizes[0];
  long n4 = n >> 2;

  char* ws = (char*)d_ws;
  Scalars* sc = (Scalars*)ws;
  unsigned* gcount = (unsigned*)(ws + 64);
  unsigned long long* gsum = (unsigned long long*)(ws + 64 + NBINS * sizeof(unsigned));
  size_t used = 64 + NBINS * sizeof(unsigned) + NBINS * sizeof(unsigned long long);

  hipMemsetAsync(d_ws, 0, used, stream);
  k_hist<<<HIST_BLOCKS, HIST_THREADS, 0, stream>>>(
      (const float4*)x, (const int4*)m, n4, x, m, n, sc, gcount, gsum);
  k_final<<<1, FIN_THREADS, 0, stream>>>(sc, gcount, gsum, (float*)d_out);
}

// Round 3
// 376.891 us; speedup vs baseline: 1.4965x; 1.4965x over previous
//
#include <hip/hip_runtime.h>

// Otsu-split loss. Round-3 structure: the per-element LDS atomic was the
// bottleneck (~6 cy per 32-bit lane-RMW on the DS pipe; rounds 1-2 both land
// at ~350-385us with 33.5M/16.7M lane-atomics respectively). Fix: bracket the
// argmin from a 1/64 subsample, then the full-data pass keeps everything in
// registers except the ~6% of elements inside the bracket (per-wave LDS hist).
//
//   f(i) = T2 - S(i)^2/i - (T-S(i))^2/(K-i)   (s2-prefix cancels)
// Split candidates: t_lo and the 64 fine-bin boundaries (width 1/256, snapped
// to the 1/256 grid so 0.0 stays a boundary -- the grid that gave absmax 0.0).

#define SBINS 1024          // subsample bins over [-4,4), width 1/128
#define FBINS 64            // fine bins, width 1/256 -> bracket width 0.25
#define MAIN_BLOCKS 2048
#define MAIN_THREADS 256
#define SAMP_BLOCKS 256
#define SAMP_THREADS 256

struct WS {
  double T, T2, Sb;                 // global totals, sum below t_lo
  double gsum[FBINS];               // fine-bin value sums (unbiased)
  unsigned long long shist[SBINS];  // subsample hist: count<<42 | q-sum
  float t_lo;
  unsigned K, Cb;                   // masked count, count below t_lo
  unsigned gcnt[FBINS];             // fine-bin counts
};

// ---------------- stage 1: subsample histogram ----------------
__global__ __launch_bounds__(SAMP_THREADS)
void k_sample(const float4* __restrict__ x4, const int4* __restrict__ m4,
              long n4, WS* __restrict__ ws) {
  __shared__ unsigned long long h[SBINS];  // 8 KiB
  for (int b = threadIdx.x; b < SBINS; b += SAMP_THREADS) h[b] = 0ull;
  __syncthreads();

  int gw = (blockIdx.x * SAMP_THREADS + threadIdx.x) >> 6;  // global wave 0..1023
  int lane = threadIdx.x & 63;
  long spacing = n4 / 2048; if (spacing < 64) spacing = 64;

#define SPROC(v_, m_)                                                  \
  if (m_) {                                                            \
    float v = (v_);                                                    \
    int b = (int)fmaf(v, 128.0f, 512.0f);                              \
    b = min(max(b, 0), SBINS - 1);                                     \
    unsigned q = __float2uint_rn(fmaf(v, 1048576.0f, 16777216.0f));    \
    atomicAdd(&h[b], (1ull << 42) + (unsigned long long)q);            \
  }

  for (int j = 0; j < 2; j++) {
    long idx = (long)(gw * 2 + j) * spacing + lane;  // 64 consecutive float4 per wave
    if (idx < n4) {
      float4 xv = x4[idx];
      int4 mv = m4[idx];
      SPROC(xv.x, mv.x) SPROC(xv.y, mv.y) SPROC(xv.z, mv.z) SPROC(xv.w, mv.w)
    }
  }
#undef SPROC

  __syncthreads();
  for (int b = threadIdx.x; b < SBINS; b += SAMP_THREADS) {
    unsigned long long v = h[b];
    if (v) atomicAdd(&ws->shist[b], v);
  }
}

// ---------------- stage 2: pick bracket ----------------
__global__ __launch_bounds__(256)
void k_pick(WS* __restrict__ ws) {
  __shared__ unsigned long long sC[256], sS[256];
  __shared__ double rf[256];
  __shared__ int rb[256];
  int t = threadIdx.x;

  unsigned long long c[4], q[4], cc = 0, qq = 0;
  for (int j = 0; j < 4; j++) {
    unsigned long long hv = ws->shist[t * 4 + j];
    c[j] = hv >> 42; q[j] = hv & ((1ull << 42) - 1ull);
    cc += c[j]; qq += q[j];
  }
  sC[t] = cc; sS[t] = qq;
  __syncthreads();
  for (int off = 1; off < 256; off <<= 1) {
    unsigned long long ac = (t >= off) ? sC[t - off] : 0ull;
    unsigned long long as = (t >= off) ? sS[t - off] : 0ull;
    __syncthreads();
    sC[t] += ac; sS[t] += as;
    __syncthreads();
  }
  unsigned long long K = sC[255], Q = sS[255];
  double Tp = (double)Q * 9.5367431640625e-07 - 16.0 * (double)K;

  unsigned long long Ci = sC[t] - cc, Qi = sS[t] - qq;
  double bestf = 1.0e300; int bestb = -1;
  for (int j = 0; j < 4; j++) {
    Ci += c[j]; Qi += q[j];
    if (Ci >= 1ull && Ci < K) {
      double di = (double)Ci;
      double S = (double)Qi * 9.5367431640625e-07 - 16.0 * di;
      double d2 = Tp - S;
      double f = -S * S / di - d2 * d2 / ((double)K - di);
      if (f < bestf) { bestf = f; bestb = t * 4 + j; }
    }
  }
  rf[t] = bestf; rb[t] = bestb;
  __syncthreads();
  for (int off = 128; off > 0; off >>= 1) {
    if (t < off && rf[t + off] < rf[t]) { rf[t] = rf[t + off]; rb[t] = rb[t + off]; }
    __syncthreads();
  }
  if (t == 0) {
    float t_lo = -0.125f;
    if (rb[0] >= 0 && K >= 2ull) {
      float that = -4.0f + (float)(rb[0] + 1) * 0.0078125f;  // right edge of bin
      t_lo = (rintf(that * 256.0f) - 32.0f) * 0.00390625f;   // snap, center bracket
    }
    ws->t_lo = t_lo;
  }
}

// ---------------- stage 3: full-data streaming pass ----------------
__global__ __launch_bounds__(MAIN_THREADS, 6)
void k_main(const float4* __restrict__ x4, const int4* __restrict__ m4, long n4,
            const float* __restrict__ xs, const int* __restrict__ ms, long n,
            WS* __restrict__ ws) {
  __shared__ unsigned long long wh[MAIN_THREADS / 64][FBINS];  // per-wave hists, 2 KiB
  __shared__ float bT[4], bT2[4], bSb[4];
  __shared__ unsigned bK[4], bCb[4];

  int wave = threadIdx.x >> 6, lane = threadIdx.x & 63;
  unsigned long long* h = wh[wave];
  ((unsigned long long*)wh)[threadIdx.x] = 0ull;  // 256 slots == 256 threads
  __syncthreads();

  float t_lo = ws->t_lo;
  unsigned K = 0, Cb = 0;
  float T = 0.0f, T2 = 0.0f, Sb = 0.0f;

#define PROC(v_, m_)                                                       \
  if (m_) {                                                                \
    float v = (v_);                                                        \
    K++; T += v; T2 = fmaf(v, v, T2);                                      \
    float rel = v - t_lo;                                                  \
    if (rel < 0.0f) { Cb++; Sb += v; }                                     \
    else {                                                                 \
      float u = rel * 256.0f;                                              \
      if (u < 64.0f) {                                                     \
        int b = (int)u;                                                    \
        unsigned q = __float2uint_rn(fmaf(v, 1048576.0f, 16777216.0f));    \
        atomicAdd(&h[b], (1ull << 42) + (unsigned long long)q);            \
      }                                                                    \
    }                                                                      \
  }
#define PROC4(xv, mv) { PROC(xv.x, mv.x) PROC(xv.y, mv.y) PROC(xv.z, mv.z) PROC(xv.w, mv.w) }

  long tid = (long)blockIdx.x * MAIN_THREADS + threadIdx.x;
  long stride = (long)MAIN_BLOCKS * MAIN_THREADS;
  if (tid < n4) {
    float4 xv = x4[tid]; int4 mv = m4[tid];
    for (long j = tid + stride; j < n4; j += stride) {
      float4 xn = x4[j]; int4 mn = m4[j];   // prefetch next iteration
      PROC4(xv, mv)
      xv = xn; mv = mn;
    }
    PROC4(xv, mv)
  }
  if (blockIdx.x == 0 && threadIdx.x == 0) {  // tail (n not multiple of 4)
    for (long i = n4 * 4; i < n; i++) { PROC(xs[i], ms[i]) }
  }
#undef PROC4
#undef PROC

  // wave reduce -> block reduce -> one global atomic set per block
  for (int off = 32; off > 0; off >>= 1) {
    K += __shfl_down(K, off);
    Cb += __shfl_down(Cb, off);
    T += __shfl_down(T, off);
    T2 += __shfl_down(T2, off);
    Sb += __shfl_down(Sb, off);
  }
  if (lane == 0) { bK[wave] = K; bCb[wave] = Cb; bT[wave] = T; bT2[wave] = T2; bSb[wave] = Sb; }
  __syncthreads();
  if (threadIdx.x == 0) {
    unsigned k = 0, cb = 0; double t = 0.0, t2 = 0.0, sb = 0.0;
    for (int w = 0; w < 4; w++) { k += bK[w]; cb += bCb[w]; t += bT[w]; t2 += bT2[w]; sb += bSb[w]; }
    atomicAdd(&ws->K, k); atomicAdd(&ws->Cb, cb);
    atomicAdd(&ws->T, t); atomicAdd(&ws->T2, t2); atomicAdd(&ws->Sb, sb);
  }
  // combine 4 wave-hists, flush nonzero bins (64 atomic pairs max per block)
  if (threadIdx.x < FBINS) {
    int b = threadIdx.x;
    unsigned long long tot = wh[0][b] + wh[1][b] + wh[2][b] + wh[3][b];
    if (tot) {
      unsigned cnt = (unsigned)(tot >> 42);
      double sum = (double)(tot & ((1ull << 42) - 1ull)) * 9.5367431640625e-07
                   - 16.0 * (double)cnt;
      atomicAdd(&ws->gcnt[b], cnt);
      atomicAdd(&ws->gsum[b], sum);
    }
  }
}

// ---------------- stage 4: final argmin + output ----------------
__global__ __launch_bounds__(64)
void k_fin(const WS* __restrict__ ws, float* __restrict__ out) {
  __shared__ double sS[FBINS];
  __shared__ unsigned sC[FBINS];
  int t = threadIdx.x;
  sS[t] = ws->gsum[t]; sC[t] = ws->gcnt[t];
  __syncthreads();
  if (t == 0) {
    unsigned Ku = ws->K;
    double kd = (double)Ku;
    double T = ws->T, T2 = ws->T2;
    double C = (double)ws->Cb, S = ws->Sb;
    double bestf = 1.0e300, bestS = 0.0, bestC = 0.0;
    // candidate at t_lo itself, then each fine-bin right edge
    for (int b = -1; b < FBINS; b++) {
      if (b >= 0) { C += (double)sC[b]; S += sS[b]; }
      if (C >= 1.0 && C < kd) {
        double d2 = T - S;
        double f = T2 - S * S / C - d2 * d2 / (kd - C);
        if (f < bestf) { bestf = f; bestS = S; bestC = C; }
      }
    }
    double result = 0.0;
    if (Ku >= 2u && bestC >= 1.0) {
      double var_tot = (T2 - T * T / kd) / kd;
      double reg = bestf / var_tot / kd;
      result = bestS / bestC + 0.5 * reg;
    }
    out[0] = (float)result;
  }
}

extern "C" void kernel_launch(void* const* d_in, const int* in_sizes, int n_in,
                              void* d_out, int out_size, void* d_ws, size_t ws_size,
                              hipStream_t stream) {
  const float* x = (const float*)d_in[0];
  const int* m = (const int*)d_in[1];
  long n = (long)in_sizes[0];
  long n4 = n >> 2;
  WS* ws = (WS*)d_ws;

  hipMemsetAsync(d_ws, 0, sizeof(WS), stream);
  k_sample<<<SAMP_BLOCKS, SAMP_THREADS, 0, stream>>>((const float4*)x, (const int4*)m, n4, ws);
  k_pick<<<1, 256, 0, stream>>>(ws);
  k_main<<<MAIN_BLOCKS, MAIN_THREADS, 0, stream>>>((const float4*)x, (const int4*)m, n4,
                                                   x, m, n, ws);
  k_fin<<<1, 64, 0, stream>>>(ws, (float*)d_out);
}

// Round 4
// 320.531 us; speedup vs baseline: 1.7597x; 1.1758x over previous
//
#include <hip/hip_runtime.h>

// Otsu-split loss. Round-4: NO global atomics anywhere (rounds 1-3 all paid a
// same-address atomic tail: block-epilogue atomicAdds to shared scalar/hist
// addresses serialize at the home cache bank, ~250cy each, non-overlappable).
// Every block now writes private partials with plain stores; tiny reduction
// kernels combine them. No memset needed (all slots fully written).
//
//   f(i) = T2 - S(i)^2/i - (T-S(i))^2/(K-i)   (s2-prefix cancels)
// Bracket [t_lo, t_lo+0.25) from a 1/64 subsample; fine bins width 1/256
// snapped to the 1/256 grid (absmax was 0.0 in rounds 1-3 on this grid).

#define SBINS 1024          // subsample bins over [-4,4), width 1/128
#define FBINS 64            // fine bins, width 1/256 -> bracket width 0.25
#define MAIN_THREADS 1024
#define SAMP_THREADS 1024
#define PICK_THREADS 256
#define FIN_THREADS 1024

// ---------------- stage 1: subsample histogram (per-block, plain stores) ----
__global__ __launch_bounds__(SAMP_THREADS)
void k_sample(const float4* __restrict__ x4, const int4* __restrict__ m4,
              long n4, unsigned long long* __restrict__ sh, int sb) {
  __shared__ unsigned long long h[SBINS];  // 8 KiB
  for (int b = threadIdx.x; b < SBINS; b += SAMP_THREADS) h[b] = 0ull;
  __syncthreads();

  int gw = (int)((blockIdx.x * SAMP_THREADS + threadIdx.x) >> 6);
  int nwaves = sb * (SAMP_THREADS / 64);
  int lane = threadIdx.x & 63;
  long spacing = n4 / 2048; if (spacing < 64) spacing = 64;

#define SPROC(v_, m_)                                                  \
  if (m_) {                                                            \
    float v = (v_);                                                    \
    int b = (int)fmaf(v, 128.0f, 512.0f);                              \
    b = min(max(b, 0), SBINS - 1);                                     \
    unsigned q = __float2uint_rn(fmaf(v, 1048576.0f, 16777216.0f));    \
    atomicAdd(&h[b], (1ull << 42) + (unsigned long long)q);            \
  }

  for (int c = gw; c < 2048; c += nwaves) {
    long idx = (long)c * spacing + lane;
    if (idx < n4) {
      float4 xv = x4[idx];
      int4 mv = m4[idx];
      SPROC(xv.x, mv.x) SPROC(xv.y, mv.y) SPROC(xv.z, mv.z) SPROC(xv.w, mv.w)
    }
  }
#undef SPROC

  __syncthreads();
  for (int b = threadIdx.x; b < SBINS; b += SAMP_THREADS)
    sh[(long)blockIdx.x * SBINS + b] = h[b];   // plain coalesced store
}

// ---------------- stage 2: reduce sample hists, pick bracket ----------------
__global__ __launch_bounds__(PICK_THREADS)
void k_pick(const unsigned long long* __restrict__ sh, int sb,
            float* __restrict__ t_lo_out) {
  __shared__ unsigned long long sC[PICK_THREADS], sS[PICK_THREADS];
  __shared__ double rf[PICK_THREADS];
  __shared__ int rb[PICK_THREADS];
  int t = threadIdx.x;

  unsigned long long c[4], q[4], cc = 0, qq = 0;
  for (int j = 0; j < 4; j++) {
    int bin = t * 4 + j;
    unsigned long long hv = 0ull;
    for (int r = 0; r < sb; r++) hv += sh[(long)r * SBINS + bin];
    c[j] = hv >> 42; q[j] = hv & ((1ull << 42) - 1ull);
    cc += c[j]; qq += q[j];
  }
  sC[t] = cc; sS[t] = qq;
  __syncthreads();
  for (int off = 1; off < PICK_THREADS; off <<= 1) {
    unsigned long long ac = (t >= off) ? sC[t - off] : 0ull;
    unsigned long long as = (t >= off) ? sS[t - off] : 0ull;
    __syncthreads();
    sC[t] += ac; sS[t] += as;
    __syncthreads();
  }
  unsigned long long K = sC[PICK_THREADS - 1], Q = sS[PICK_THREADS - 1];
  double Tp = (double)Q * 9.5367431640625e-07 - 16.0 * (double)K;

  unsigned long long Ci = sC[t] - cc, Qi = sS[t] - qq;
  double bestf = 1.0e300; int bestb = -1;
  for (int j = 0; j < 4; j++) {
    Ci += c[j]; Qi += q[j];
    if (Ci >= 1ull && Ci < K) {
      double di = (double)Ci;
      double S = (double)Qi * 9.5367431640625e-07 - 16.0 * di;
      double d2 = Tp - S;
      double f = -S * S / di - d2 * d2 / ((double)K - di);
      if (f < bestf) { bestf = f; bestb = t * 4 + j; }
    }
  }
  rf[t] = bestf; rb[t] = bestb;
  __syncthreads();
  for (int off = PICK_THREADS / 2; off > 0; off >>= 1) {
    if (t < off && rf[t + off] < rf[t]) { rf[t] = rf[t + off]; rb[t] = rb[t + off]; }
    __syncthreads();
  }
  if (t == 0) {
    float t_lo = -0.125f;
    if (rb[0] >= 0 && K >= 2ull) {
      float that = -4.0f + (float)(rb[0] + 1) * 0.0078125f;  // right edge of bin
      t_lo = (rintf(that * 256.0f) - 32.0f) * 0.00390625f;   // snap, center bracket
    }
    *t_lo_out = t_lo;
  }
}

// ---------------- stage 3: full-data streaming pass ----------------
__global__ __launch_bounds__(MAIN_THREADS, 8)
void k_main(const float4* __restrict__ x4, const int4* __restrict__ m4, long n4,
            const float* __restrict__ xs, const int* __restrict__ ms, long n,
            const float* __restrict__ t_lo_p,
            double* __restrict__ Tb, double* __restrict__ T2b,
            double* __restrict__ Sbb, unsigned* __restrict__ Kb,
            unsigned* __restrict__ Cbb, unsigned long long* __restrict__ mh,
            int mb) {
  __shared__ unsigned long long wh[MAIN_THREADS / 64][FBINS];  // 8 KiB
  __shared__ float bT[16], bT2[16], bSb[16];
  __shared__ unsigned bK[16], bCb[16];

  int wave = threadIdx.x >> 6, lane = threadIdx.x & 63;
  unsigned long long* h = wh[wave];
  ((unsigned long long*)wh)[threadIdx.x] = 0ull;  // 1024 slots == 1024 threads
  __syncthreads();

  float t_lo = *t_lo_p;
  unsigned K = 0, Cb = 0;
  float T = 0.0f, T2 = 0.0f, Sb = 0.0f;

#define PROC(v_, m_)                                                       \
  {                                                                        \
    bool mm = (m_) != 0;                                                   \
    float v = (v_);                                                        \
    float vm = mm ? v : 0.0f;                                              \
    K += mm; T += vm; T2 = fmaf(vm, vm, T2);                               \
    bool below = mm && (v < t_lo);                                         \
    Cb += below; Sb += below ? v : 0.0f;                                   \
    float rel = v - t_lo;                                                  \
    if (mm && rel >= 0.0f && rel < 0.25f) {                                \
      int b = (int)(rel * 256.0f);                                         \
      unsigned q = __float2uint_rn(fmaf(v, 1048576.0f, 16777216.0f));      \
      atomicAdd(&h[b], (1ull << 42) + (unsigned long long)q);              \
    }                                                                      \
  }
#define PROC4(xv, mv) { PROC(xv.x, mv.x) PROC(xv.y, mv.y) PROC(xv.z, mv.z) PROC(xv.w, mv.w) }

  long tid = (long)blockIdx.x * MAIN_THREADS + threadIdx.x;
  long stride = (long)mb * MAIN_THREADS;
  if (tid < n4) {
    float4 xv = x4[tid]; int4 mv = m4[tid];
    for (long j = tid + stride; j < n4; j += stride) {
      float4 xn = x4[j]; int4 mn = m4[j];   // prefetch next iteration
      PROC4(xv, mv)
      xv = xn; mv = mn;
    }
    PROC4(xv, mv)
  }
  if (blockIdx.x == 0 && threadIdx.x == 0) {  // tail (n not multiple of 4)
    for (long i = n4 * 4; i < n; i++) { PROC(xs[i], ms[i]) }
  }
#undef PROC4
#undef PROC

  // wave shuffle reduce -> block reduce -> PLAIN per-block stores (no atomics)
  for (int off = 32; off > 0; off >>= 1) {
    K += __shfl_down(K, off);
    Cb += __shfl_down(Cb, off);
    T += __shfl_down(T, off);
    T2 += __shfl_down(T2, off);
    Sb += __shfl_down(Sb, off);
  }
  if (lane == 0) { bK[wave] = K; bCb[wave] = Cb; bT[wave] = T; bT2[wave] = T2; bSb[wave] = Sb; }
  __syncthreads();
  if (threadIdx.x == 0) {
    unsigned k = 0, cb = 0; double t = 0.0, t2 = 0.0, sb_ = 0.0;
    for (int w = 0; w < 16; w++) {
      k += bK[w]; cb += bCb[w]; t += (double)bT[w]; t2 += (double)bT2[w]; sb_ += (double)bSb[w];
    }
    Kb[blockIdx.x] = k; Cbb[blockIdx.x] = cb;
    Tb[blockIdx.x] = t; T2b[blockIdx.x] = t2; Sbb[blockIdx.x] = sb_;
  }
  if (threadIdx.x < FBINS) {
    int b = threadIdx.x;
    unsigned long long tot = 0ull;
    for (int w = 0; w < MAIN_THREADS / 64; w++) tot += wh[w][b];
    mh[(long)blockIdx.x * FBINS + b] = tot;   // plain coalesced store
  }
}

// ---------------- stage 4: reduce partials, argmin, output ----------------
__global__ __launch_bounds__(FIN_THREADS)
void k_fin(const double* __restrict__ Tb, const double* __restrict__ T2b,
           const double* __restrict__ Sbb, const unsigned* __restrict__ Kb,
           const unsigned* __restrict__ Cbb,
           const unsigned long long* __restrict__ mh, int mb,
           float* __restrict__ out) {
  __shared__ double lT[16], lT2[16], lSb[16];
  __shared__ unsigned long long lK[16], lCb[16];
  __shared__ unsigned long long pc[16][FBINS], pq[16][FBINS];
  __shared__ double gT, gT2, gSb;
  __shared__ unsigned long long gK, gCb;

  int t = threadIdx.x;
  int wave = t >> 6, lane = t & 63;

  // ---- scalar totals ----
  double T = 0.0, T2 = 0.0, Sb = 0.0;
  unsigned long long K = 0, Cb = 0;
  for (int i = t; i < mb; i += FIN_THREADS) {
    T += Tb[i]; T2 += T2b[i]; Sb += Sbb[i];
    K += Kb[i]; Cb += Cbb[i];
  }
  for (int off = 32; off > 0; off >>= 1) {
    T += __shfl_down(T, off); T2 += __shfl_down(T2, off); Sb += __shfl_down(Sb, off);
    K += __shfl_down(K, off); Cb += __shfl_down(Cb, off);
  }
  if (lane == 0) { lT[wave] = T; lT2[wave] = T2; lSb[wave] = Sb; lK[wave] = K; lCb[wave] = Cb; }

  // ---- hist totals: group (t>>6) strides blocks, lane = bin ----
  unsigned long long hc = 0, hq = 0;
  for (int i = wave; i < mb; i += 16) {
    unsigned long long v = mh[(long)i * FBINS + lane];
    hc += v >> 42; hq += v & ((1ull << 42) - 1ull);
  }
  pc[wave][lane] = hc; pq[wave][lane] = hq;
  __syncthreads();

  if (t == 0) {
    double a = 0, b = 0, c = 0; unsigned long long k = 0, cb = 0;
    for (int w = 0; w < 16; w++) { a += lT[w]; b += lT2[w]; c += lSb[w]; k += lK[w]; cb += lCb[w]; }
    gT = a; gT2 = b; gSb = c; gK = k; gCb = cb;
  }
  __syncthreads();

  if (t < FBINS) {  // wave 0 finishes
    unsigned long long c = 0, q = 0;
    for (int w = 0; w < 16; w++) { c += pc[w][t]; q += pq[w][t]; }
    // inclusive scan over 64 bins (shuffle)
    for (int off = 1; off < 64; off <<= 1) {
      unsigned long long cc = __shfl_up(c, off);
      unsigned long long qq = __shfl_up(q, off);
      if (lane >= off) { c += cc; q += qq; }
    }
    double kd = (double)gK;
    double T_ = gT, T2_ = gT2;
    double Ccand = (double)gCb + (double)c;
    double Scand = gSb + ((double)q * 9.5367431640625e-07 - 16.0 * (double)c);
    double f = 1.0e300;
    if (Ccand >= 1.0 && Ccand < kd) {
      double d2 = T_ - Scand;
      f = T2_ - Scand * Scand / Ccand - d2 * d2 / (kd - Ccand);
    }
    if (lane == 0) {  // extra candidate: split exactly at t_lo (empty prefix)
      double C0 = (double)gCb, S0 = gSb;
      if (C0 >= 1.0 && C0 < kd) {
        double d2 = T_ - S0;
        double f0 = T2_ - S0 * S0 / C0 - d2 * d2 / (kd - C0);
        if (f0 < f) { f = f0; Ccand = C0; Scand = S0; }
      }
    }
    for (int off = 32; off > 0; off >>= 1) {
      double of = __shfl_down(f, off);
      double oS = __shfl_down(Scand, off);
      double oC = __shfl_down(Ccand, off);
      if (of < f) { f = of; Scand = oS; Ccand = oC; }
    }
    if (lane == 0) {
      double result = 0.0;
      if (gK >= 2ull && f < 1.0e300 && Ccand >= 1.0) {
        double var_tot = (T2_ - T_ * T_ / kd) / kd;
        double reg = f / var_tot / kd;
        result = Scand / Ccand + 0.5 * reg;
      }
      out[0] = (float)result;
    }
  }
}

extern "C" void kernel_launch(void* const* d_in, const int* in_sizes, int n_in,
                              void* d_out, int out_size, void* d_ws, size_t ws_size,
                              hipStream_t stream) {
  const float* x = (const float*)d_in[0];
  const int* m = (const int*)d_in[1];
  long n = (long)in_sizes[0];
  long n4 = n >> 2;

  // choose block counts to fit ws_size (deterministic per capture)
  int mb = 512, sb = 32;
  size_t need;
  for (;;) {
    need = 64 + (size_t)mb * (3 * sizeof(double) + 2 * sizeof(unsigned))
         + (size_t)mb * FBINS * 8 + (size_t)sb * SBINS * 8 + 64;
    if (need <= ws_size || (mb <= 64 && sb <= 8)) break;
    if (mb > 64) mb >>= 1;
    else sb >>= 1;
  }

  char* p = (char*)d_ws;
  float* t_lo = (float*)p;
  double* Tb = (double*)(p + 64);
  double* T2b = Tb + mb;
  double* Sbb = T2b + mb;
  unsigned long long* mh = (unsigned long long*)(Sbb + mb);
  unsigned* Kb = (unsigned*)(mh + (size_t)mb * FBINS);
  unsigned* Cbb = Kb + mb;
  unsigned long long* sh =
      (unsigned long long*)(((uintptr_t)(Cbb + mb) + 7) & ~(uintptr_t)7);

  k_sample<<<sb, SAMP_THREADS, 0, stream>>>((const float4*)x, (const int4*)m, n4, sh, sb);
  k_pick<<<1, PICK_THREADS, 0, stream>>>(sh, sb, t_lo);
  k_main<<<mb, MAIN_THREADS, 0, stream>>>((const float4*)x, (const int4*)m, n4,
                                          x, m, n, t_lo, Tb, T2b, Sbb, Kb, Cbb, mh, mb);
  k_fin<<<1, FIN_THREADS, 0, stream>>>(Tb, T2b, Sbb, Kb, Cbb, mh, mb, (float*)d_out);
}

// Round 5
// 318.360 us; speedup vs baseline: 1.7717x; 1.0068x over previous
//
#include <hip/hip_runtime.h>

// Otsu-split loss. Round-5: k_main is the only controllable cost (the ~210us
// total-minus-k_main gap is harness reset overhead, constant across rounds
// 1-4). Two changes vs round 4 (102us k_main @ 2.6 TB/s effective):
//  (a) bracket 64->32 fine bins (+-1/16 around subsample argmin; jitter of the
//      262k-sample argmin is ~0.005, >=10x margin) -> halves in-bracket LDS
//      u64 atomics (~35us -> ~18us of DS-pipe occupancy).
//  (b) 2x-unrolled main loop with depth-1 prefetch: 4 (float4,int4) pairs in
//      flight per thread instead of 2 (MLP), VGPR ~50 (< 64 for 8 waves/EU).
//
//   f(i) = T2 - S(i)^2/i - (T-S(i))^2/(K-i)   (s2-prefix cancels)
// Candidates on the 1/256 grid (absmax 0.0 in rounds 1-4 on this grid).

#define SBINS 1024          // subsample bins over [-4,4), width 1/128
#define FBINS 32            // fine bins, width 1/256 -> bracket width 1/8
#define MAIN_THREADS 1024
#define SAMP_THREADS 1024
#define PICK_THREADS 256
#define FIN_THREADS 1024

// ---------------- stage 1: subsample histogram (per-block, plain stores) ----
__global__ __launch_bounds__(SAMP_THREADS)
void k_sample(const float4* __restrict__ x4, const int4* __restrict__ m4,
              long n4, unsigned long long* __restrict__ sh, int sb) {
  __shared__ unsigned long long h[SBINS];  // 8 KiB
  for (int b = threadIdx.x; b < SBINS; b += SAMP_THREADS) h[b] = 0ull;
  __syncthreads();

  int gw = (int)((blockIdx.x * SAMP_THREADS + threadIdx.x) >> 6);
  int nwaves = sb * (SAMP_THREADS / 64);
  int lane = threadIdx.x & 63;
  long spacing = n4 / 2048; if (spacing < 64) spacing = 64;

#define SPROC(v_, m_)                                                  \
  if (m_) {                                                            \
    float v = (v_);                                                    \
    int b = (int)fmaf(v, 128.0f, 512.0f);                              \
    b = min(max(b, 0), SBINS - 1);                                     \
    unsigned q = __float2uint_rn(fmaf(v, 1048576.0f, 16777216.0f));    \
    atomicAdd(&h[b], (1ull << 42) + (unsigned long long)q);            \
  }

  for (int c = gw; c < 2048; c += nwaves) {
    long idx = (long)c * spacing + lane;
    if (idx < n4) {
      float4 xv = x4[idx];
      int4 mv = m4[idx];
      SPROC(xv.x, mv.x) SPROC(xv.y, mv.y) SPROC(xv.z, mv.z) SPROC(xv.w, mv.w)
    }
  }
#undef SPROC

  __syncthreads();
  for (int b = threadIdx.x; b < SBINS; b += SAMP_THREADS)
    sh[(long)blockIdx.x * SBINS + b] = h[b];   // plain coalesced store
}

// ---------------- stage 2: reduce sample hists, pick bracket ----------------
__global__ __launch_bounds__(PICK_THREADS)
void k_pick(const unsigned long long* __restrict__ sh, int sb,
            float* __restrict__ t_lo_out) {
  __shared__ unsigned long long sC[PICK_THREADS], sS[PICK_THREADS];
  __shared__ double rf[PICK_THREADS];
  __shared__ int rb[PICK_THREADS];
  int t = threadIdx.x;

  unsigned long long c[4], q[4], cc = 0, qq = 0;
  for (int j = 0; j < 4; j++) {
    int bin = t * 4 + j;
    unsigned long long hv = 0ull;
    for (int r = 0; r < sb; r++) hv += sh[(long)r * SBINS + bin];
    c[j] = hv >> 42; q[j] = hv & ((1ull << 42) - 1ull);
    cc += c[j]; qq += q[j];
  }
  sC[t] = cc; sS[t] = qq;
  __syncthreads();
  for (int off = 1; off < PICK_THREADS; off <<= 1) {
    unsigned long long ac = (t >= off) ? sC[t - off] : 0ull;
    unsigned long long as = (t >= off) ? sS[t - off] : 0ull;
    __syncthreads();
    sC[t] += ac; sS[t] += as;
    __syncthreads();
  }
  unsigned long long K = sC[PICK_THREADS - 1], Q = sS[PICK_THREADS - 1];
  double Tp = (double)Q * 9.5367431640625e-07 - 16.0 * (double)K;

  unsigned long long Ci = sC[t] - cc, Qi = sS[t] - qq;
  double bestf = 1.0e300; int bestb = -1;
  for (int j = 0; j < 4; j++) {
    Ci += c[j]; Qi += q[j];
    if (Ci >= 1ull && Ci < K) {
      double di = (double)Ci;
      double S = (double)Qi * 9.5367431640625e-07 - 16.0 * di;
      double d2 = Tp - S;
      double f = -S * S / di - d2 * d2 / ((double)K - di);
      if (f < bestf) { bestf = f; bestb = t * 4 + j; }
    }
  }
  rf[t] = bestf; rb[t] = bestb;
  __syncthreads();
  for (int off = PICK_THREADS / 2; off > 0; off >>= 1) {
    if (t < off && rf[t + off] < rf[t]) { rf[t] = rf[t + off]; rb[t] = rb[t + off]; }
    __syncthreads();
  }
  if (t == 0) {
    float t_lo = -0.0625f;
    if (rb[0] >= 0 && K >= 2ull) {
      float that = -4.0f + (float)(rb[0] + 1) * 0.0078125f;  // right edge of bin
      // snap to 1/256 grid, center the 32-bin bracket (16 bins each side)
      t_lo = (rintf(that * 256.0f) - 16.0f) * 0.00390625f;
    }
    *t_lo_out = t_lo;
  }
}

// ---------------- stage 3: full-data streaming pass ----------------
__global__ __launch_bounds__(MAIN_THREADS, 8)
void k_main(const float4* __restrict__ x4, const int4* __restrict__ m4, long n4,
            const float* __restrict__ xs, const int* __restrict__ ms, long n,
            const float* __restrict__ t_lo_p,
            double* __restrict__ Tb, double* __restrict__ T2b,
            double* __restrict__ Sbb, unsigned* __restrict__ Kb,
            unsigned* __restrict__ Cbb, unsigned long long* __restrict__ mh,
            int nblk) {
  __shared__ unsigned long long wh[MAIN_THREADS / 64][FBINS];  // 4 KiB
  __shared__ float bT[16], bT2[16], bSb[16];
  __shared__ unsigned bK[16], bCb[16];

  int wave = threadIdx.x >> 6, lane = threadIdx.x & 63;
  unsigned long long* h = wh[wave];
  if (threadIdx.x < (MAIN_THREADS / 64) * FBINS)
    ((unsigned long long*)wh)[threadIdx.x] = 0ull;
  __syncthreads();

  float t_lo = *t_lo_p;
  unsigned K = 0, Cb = 0;
  float T = 0.0f, T2 = 0.0f, Sb = 0.0f;

#define PROC(v_, m_)                                                       \
  {                                                                        \
    bool mm = (m_) != 0;                                                   \
    float v = (v_);                                                        \
    float vm = mm ? v : 0.0f;                                              \
    K += mm; T += vm; T2 = fmaf(vm, vm, T2);                               \
    bool below = mm && (v < t_lo);                                         \
    Cb += below; Sb += below ? v : 0.0f;                                   \
    float rel = v - t_lo;                                                  \
    if (mm && rel >= 0.0f && rel < 0.125f) {                               \
      int b = (int)(rel * 256.0f);                                         \
      unsigned q = __float2uint_rn(fmaf(v, 1048576.0f, 16777216.0f));      \
      atomicAdd(&h[b], (1ull << 42) + (unsigned long long)q);              \
    }                                                                      \
  }
#define PROC4(xv, mv) { PROC(xv.x, mv.x) PROC(xv.y, mv.y) PROC(xv.z, mv.z) PROC(xv.w, mv.w) }

  long tid0 = (long)blockIdx.x * MAIN_THREADS + threadIdx.x;
  long s = (long)nblk * MAIN_THREADS;
  long step = 2 * s;
  if (tid0 < n4) {
    float4 xa = x4[tid0]; int4 ma = m4[tid0];
    float4 xb; int4 mb2;
    bool hb = (tid0 + s) < n4;
    if (hb) { xb = x4[tid0 + s]; mb2 = m4[tid0 + s]; }
    for (long j = tid0 + step; j < n4; j += step) {
      float4 na = x4[j]; int4 nma = m4[j];      // prefetch next pair
      float4 nb; int4 nmb;
      bool nhb = (j + s) < n4;
      if (nhb) { nb = x4[j + s]; nmb = m4[j + s]; }
      PROC4(xa, ma)
      if (hb) { PROC4(xb, mb2) }
      xa = na; ma = nma; xb = nb; mb2 = nmb; hb = nhb;
    }
    PROC4(xa, ma)
    if (hb) { PROC4(xb, mb2) }
  }
  if (blockIdx.x == 0 && threadIdx.x == 0) {  // tail (n not multiple of 4)
    for (long i = n4 * 4; i < n; i++) { PROC(xs[i], ms[i]) }
  }
#undef PROC4
#undef PROC

  // wave shuffle reduce -> block reduce -> PLAIN per-block stores (no atomics)
  for (int off = 32; off > 0; off >>= 1) {
    K += __shfl_down(K, off);
    Cb += __shfl_down(Cb, off);
    T += __shfl_down(T, off);
    T2 += __shfl_down(T2, off);
    Sb += __shfl_down(Sb, off);
  }
  if (lane == 0) { bK[wave] = K; bCb[wave] = Cb; bT[wave] = T; bT2[wave] = T2; bSb[wave] = Sb; }
  __syncthreads();
  if (threadIdx.x == 0) {
    unsigned k = 0, cb = 0; double t = 0.0, t2 = 0.0, sb_ = 0.0;
    for (int w = 0; w < 16; w++) {
      k += bK[w]; cb += bCb[w]; t += (double)bT[w]; t2 += (double)bT2[w]; sb_ += (double)bSb[w];
    }
    Kb[blockIdx.x] = k; Cbb[blockIdx.x] = cb;
    Tb[blockIdx.x] = t; T2b[blockIdx.x] = t2; Sbb[blockIdx.x] = sb_;
  }
  if (threadIdx.x < FBINS) {
    int b = threadIdx.x;
    unsigned long long tot = 0ull;
    for (int w = 0; w < MAIN_THREADS / 64; w++) tot += wh[w][b];
    mh[(long)blockIdx.x * FBINS + b] = tot;   // plain coalesced store
  }
}

// ---------------- stage 4: reduce partials, argmin, output ----------------
__global__ __launch_bounds__(FIN_THREADS)
void k_fin(const double* __restrict__ Tb, const double* __restrict__ T2b,
           const double* __restrict__ Sbb, const unsigned* __restrict__ Kb,
           const unsigned* __restrict__ Cbb,
           const unsigned long long* __restrict__ mh, int nblk,
           float* __restrict__ out) {
  __shared__ double lT[16], lT2[16], lSb[16];
  __shared__ unsigned long long lK[16], lCb[16];
  __shared__ unsigned long long pc[32][FBINS], pq[32][FBINS];  // 16 KiB
  __shared__ double gT, gT2, gSb;
  __shared__ unsigned long long gK, gCb;

  int t = threadIdx.x;
  int wave = t >> 6, lane = t & 63;

  // ---- scalar totals ----
  double T = 0.0, T2 = 0.0, Sb = 0.0;
  unsigned long long K = 0, Cb = 0;
  for (int i = t; i < nblk; i += FIN_THREADS) {
    T += Tb[i]; T2 += T2b[i]; Sb += Sbb[i];
    K += Kb[i]; Cb += Cbb[i];
  }
  for (int off = 32; off > 0; off >>= 1) {
    T += __shfl_down(T, off); T2 += __shfl_down(T2, off); Sb += __shfl_down(Sb, off);
    K += __shfl_down(K, off); Cb += __shfl_down(Cb, off);
  }
  if (lane == 0) { lT[wave] = T; lT2[wave] = T2; lSb[wave] = Sb; lK[wave] = K; lCb[wave] = Cb; }

  // ---- hist totals: thread -> (chunk = t>>5, bin = t&31), chunks stride blocks
  {
    int chunk = t >> 5, bin = t & 31;
    if (chunk < 32) {
      unsigned long long hc = 0, hq = 0;
      for (int i = chunk; i < nblk; i += 32) {
        unsigned long long v = mh[(long)i * FBINS + bin];
        hc += v >> 42; hq += v & ((1ull << 42) - 1ull);
      }
      pc[chunk][bin] = hc; pq[chunk][bin] = hq;
    }
  }
  __syncthreads();

  if (t == 0) {
    double a = 0, b = 0, c = 0; unsigned long long k = 0, cb = 0;
    for (int w = 0; w < 16; w++) { a += lT[w]; b += lT2[w]; c += lSb[w]; k += lK[w]; cb += lCb[w]; }
    gT = a; gT2 = b; gSb = c; gK = k; gCb = cb;
  }
  __syncthreads();

  if (t < 64) {  // wave 0: bins in lanes 0..31, lanes 32..63 ride along
    bool valid = lane < FBINS;
    unsigned long long c = 0, q = 0;
    if (valid) for (int w = 0; w < 32; w++) { c += pc[w][lane]; q += pq[w][lane]; }
    // inclusive scan over 32 bins (full-wave shuffles; upper lanes junk)
    for (int off = 1; off < FBINS; off <<= 1) {
      unsigned long long cc = __shfl_up(c, off);
      unsigned long long qq = __shfl_up(q, off);
      if (lane >= off && valid) { c += cc; q += qq; }
    }
    double kd = (double)gK;
    double T_ = gT, T2_ = gT2;
    double Ccand = 0.0, Scand = 0.0, f = 1.0e300;
    if (valid) {
      Ccand = (double)gCb + (double)c;
      Scand = gSb + ((double)q * 9.5367431640625e-07 - 16.0 * (double)c);
      if (Ccand >= 1.0 && Ccand < kd) {
        double d2 = T_ - Scand;
        f = T2_ - Scand * Scand / Ccand - d2 * d2 / (kd - Ccand);
      } else {
        f = 1.0e300;
      }
      if (lane == 0) {  // extra candidate: split exactly at t_lo (empty prefix)
        double C0 = (double)gCb, S0 = gSb;
        if (C0 >= 1.0 && C0 < kd) {
          double d2 = T_ - S0;
          double f0 = T2_ - S0 * S0 / C0 - d2 * d2 / (kd - C0);
          if (f0 < f) { f = f0; Ccand = C0; Scand = S0; }
        }
      }
    }
    for (int off = 32; off > 0; off >>= 1) {
      double of = __shfl_down(f, off);
      double oS = __shfl_down(Scand, off);
      double oC = __shfl_down(Ccand, off);
      if (of < f) { f = of; Scand = oS; Ccand = oC; }
    }
    if (lane == 0) {
      double result = 0.0;
      if (gK >= 2ull && f < 1.0e300 && Ccand >= 1.0) {
        double var_tot = (T2_ - T_ * T_ / kd) / kd;
        double reg = f / var_tot / kd;
        result = Scand / Ccand + 0.5 * reg;
      }
      out[0] = (float)result;
    }
  }
}

extern "C" void kernel_launch(void* const* d_in, const int* in_sizes, int n_in,
                              void* d_out, int out_size, void* d_ws, size_t ws_size,
                              hipStream_t stream) {
  const float* x = (const float*)d_in[0];
  const int* m = (const int*)d_in[1];
  long n = (long)in_sizes[0];
  long n4 = n >> 2;

  // choose block counts to fit ws_size (deterministic per capture)
  int mb = 512, sb = 32;
  size_t need;
  for (;;) {
    need = 64 + (size_t)mb * (3 * sizeof(double) + 2 * sizeof(unsigned))
         + (size_t)mb * FBINS * 8 + (size_t)sb * SBINS * 8 + 64;
    if (need <= ws_size || (mb <= 64 && sb <= 8)) break;
    if (mb > 64) mb >>= 1;
    else sb >>= 1;
  }

  char* p = (char*)d_ws;
  float* t_lo = (float*)p;
  double* Tb = (double*)(p + 64);
  double* T2b = Tb + mb;
  double* Sbb = T2b + mb;
  unsigned long long* mh = (unsigned long long*)(Sbb + mb);
  unsigned* Kb = (unsigned*)(mh + (size_t)mb * FBINS);
  unsigned* Cbb = Kb + mb;
  unsigned long long* sh =
      (unsigned long long*)(((uintptr_t)(Cbb + mb) + 7) & ~(uintptr_t)7);

  k_sample<<<sb, SAMP_THREADS, 0, stream>>>((const float4*)x, (const int4*)m, n4, sh, sb);
  k_pick<<<1, PICK_THREADS, 0, stream>>>(sh, sb, t_lo);
  k_main<<<mb, MAIN_THREADS, 0, stream>>>((const float4*)x, (const int4*)m, n4,
                                          x, m, n, t_lo, Tb, T2b, Sbb, Kb, Cbb, mh, mb);
  k_fin<<<1, FIN_THREADS, 0, stream>>>(Tb, T2b, Sbb, Kb, Cbb, mh, mb, (float*)d_out);
}